// Round 2
// baseline (217.267 us; speedup 1.0000x reference)
//
#include <hip/hip_runtime.h>

#define EPSF 1e-8f

constexpr int B_  = 16;
constexpr int C_  = 32;
constexpr int O_  = 32;
constexpr int HW  = 196;    // 14*14
constexpr int S9  = 9;
constexpr int T9  = 9;
constexpr int CH  = 64;     // hw rows per chunk
constexpr int NCH = 4;      // 64,64,64,4
constexpr int ROWF = 12;    // padded floats per (hw,t) row
constexpr int CHUNK_F = CH * T9 * ROWF;   // 6912 floats per LDS buffer
constexpr int PART_N = B_ * O_ * T9 * C_; // 147456
constexpr int XT_N = C_ * B_ * S9 * HW;   // 903168
constexpr int PT_N = C_ * B_ * HW;        // 100352

// ---------------------------------------------------------------------------
// Kernel P: transpose x -> xT[c][b][s][hw] (scaled by 0.1), p -> pT[c][b][hw]
// so kernel A's per-lane hw reads are coalesced.
// ---------------------------------------------------------------------------
__global__ __launch_bounds__(256) void caps_pre(
    const float* __restrict__ x, const float* __restrict__ p,
    float* __restrict__ xT, float* __restrict__ pT)
{
    const int idx = blockIdx.x * 256 + threadIdx.x;
    const int stride = gridDim.x * 256;
    for (int m = idx; m < XT_N; m += stride) {
        const int hw = m % HW;
        const int r  = m / HW;       // (c*B + b)*9 + s
        const int s  = r % 9;
        const int r2 = r / 9;        // c*B + b
        const int b  = r2 % B_;
        const int c  = r2 / B_;
        xT[m] = 0.1f * x[((size_t)((b * C_ + c) * HW) + hw) * 9 + s];
    }
    for (int m = idx; m < PT_N; m += stride) {
        const int hw = m % HW;
        const int r2 = m / HW;       // c*B + b
        const int b  = r2 % B_;
        const int c  = r2 / B_;
        pT[m] = p[(size_t)(b * C_ + c) * HW + hw];
    }
}

// ---------------------------------------------------------------------------
// Kernel A: per (c,o) block. wave = 4-b group, lane = hw row.
// Double-buffered LDS T staging; each LDS T-row read serves 4 b's.
// ---------------------------------------------------------------------------
__global__ __launch_bounds__(256, 2) void caps_main(
    const float* __restrict__ T,
    const float* __restrict__ xT, const float* __restrict__ pT,
    float* __restrict__ part1,    // [b][o][t][c]
    float* __restrict__ part2)
{
    const int c   = blockIdx.x;
    const int o   = blockIdx.y;
    const int tid = threadIdx.x;
    const int w   = tid >> 6;    // wave id = b-group (0..3)
    const int l   = tid & 63;    // lane = hw row within chunk

    __shared__ float tsh[2][CHUNK_F];

    const float* Tb = T + (size_t)(c * O_ + o) * (HW * 81);

    float acc1[4][9], acc2[4][9];
#pragma unroll
    for (int j = 0; j < 4; ++j)
#pragma unroll
        for (int t = 0; t < 9; ++t) { acc1[j][t] = 0.f; acc2[j][t] = 0.f; }

    // prologue: stage chunk 0 into buffer 0 (coalesced float4 + padded write)
    {
        const float4* g4 = (const float4*)Tb;
#pragma unroll
        for (int q = 0; q < 6; ++q) {
            const int i = tid + q * 256;
            if (i < 1296) {
                const float4 v = g4[i];
                const int e = i * 4;
#pragma unroll
                for (int k2 = 0; k2 < 4; ++k2) {
                    const int e2 = e + k2;
                    tsh[0][e2 + 3 * (e2 / 9)] = ((const float*)&v)[k2];
                }
            }
        }
    }
    __syncthreads();

    for (int k = 0; k < NCH; ++k) {
        const int cur = k & 1;
        const int hw0 = k * CH;
        const int R   = (HW - hw0 < CH) ? (HW - hw0) : CH;

        // issue next-chunk global loads early (latency hides under compute)
        float4 pf4[6];
        int nf4n = 0;
        if (k + 1 < NCH) {
            const int hw0n = hw0 + CH;
            const int Rn = (HW - hw0n < CH) ? (HW - hw0n) : CH;
            nf4n = (Rn * 81) >> 2;
            const float4* g4 = (const float4*)(Tb + (size_t)hw0n * 81);
#pragma unroll
            for (int q = 0; q < 6; ++q) {
                const int i = tid + q * 256;
                if (i < nf4n) pf4[q] = g4[i];
            }
        }

        // compute on current buffer
        if (l < R) {
            const int hw = hw0 + l;
            float xr[4][9], pw[4];
#pragma unroll
            for (int j = 0; j < 4; ++j) {
                const int b = w * 4 + j;
                const float* xg = xT + (size_t)(c * B_ + b) * 9 * HW + hw;
#pragma unroll
                for (int s = 0; s < 9; ++s) xr[j][s] = xg[(size_t)s * HW];
                pw[j] = pT[(size_t)(c * B_ + b) * HW + hw];
            }
            const float* rowb = &tsh[cur][l * 108];
#pragma unroll
            for (int t = 0; t < 9; ++t) {
                const float4 ta = *(const float4*)(rowb + t * 12);
                const float4 tb = *(const float4*)(rowb + t * 12 + 4);
                const float t8  = rowb[t * 12 + 8];
#pragma unroll
                for (int j = 0; j < 4; ++j) {
                    float pr = ta.x * xr[j][0];
                    pr = fmaf(ta.y, xr[j][1], pr);
                    pr = fmaf(ta.z, xr[j][2], pr);
                    pr = fmaf(ta.w, xr[j][3], pr);
                    pr = fmaf(tb.x, xr[j][4], pr);
                    pr = fmaf(tb.y, xr[j][5], pr);
                    pr = fmaf(tb.z, xr[j][6], pr);
                    pr = fmaf(tb.w, xr[j][7], pr);
                    pr = fmaf(t8,   xr[j][8], pr);
                    const float q1 = pw[j] * pr;
                    acc1[j][t] += q1;
                    acc2[j][t] = fmaf(q1, pr, acc2[j][t]);
                }
            }
        }

        // write prefetched chunk to the other buffer
        if (k + 1 < NCH) {
#pragma unroll
            for (int q = 0; q < 6; ++q) {
                const int i = tid + q * 256;
                if (i < nf4n) {
                    const int e = i * 4;
#pragma unroll
                    for (int k2 = 0; k2 < 4; ++k2) {
                        const int e2 = e + k2;
                        tsh[cur ^ 1][e2 + 3 * (e2 / 9)] = ((const float*)&pf4[q])[k2];
                    }
                }
            }
        }
        __syncthreads();
    }

    // reduce over the 64 hw-lanes of each wave; lane 0 writes b = w*4+j
#pragma unroll
    for (int j = 0; j < 4; ++j) {
#pragma unroll
        for (int t = 0; t < 9; ++t) {
            float v1 = acc1[j][t], v2 = acc2[j][t];
#pragma unroll
            for (int m = 1; m < 64; m <<= 1) {
                v1 += __shfl_xor(v1, m, 64);
                v2 += __shfl_xor(v2, m, 64);
            }
            if (l == 0) {
                const int b = w * 4 + j;
                const size_t base = ((size_t)(b * O_ + o) * 9 + t) * C_ + c;
                part1[base] = v1;
                part2[base] = v2;
            }
        }
    }
}

// ---------------------------------------------------------------------------
// Kernel B: per-b finalize. psum, c-reduction (float4), caps/var/vs/p_upd.
// ---------------------------------------------------------------------------
__global__ __launch_bounds__(256) void caps_final(
    const float* __restrict__ p,
    const float* __restrict__ part1, const float* __restrict__ part2,
    float* __restrict__ out)          // caps [B][O][9] then p_updated [B][O]
{
    const int b   = blockIdx.x;
    const int tid = threadIdx.x;

    __shared__ float vlds[O_ * T9];
    __shared__ float red[4];
    __shared__ float s_psum;

    const float* pb = p + (size_t)b * (C_ * HW);
    float a = 0.f;
    for (int i = tid; i < C_ * HW; i += 256) a += pb[i];
#pragma unroll
    for (int m = 1; m < 64; m <<= 1) a += __shfl_xor(a, m, 64);
    if ((tid & 63) == 0) red[tid >> 6] = a;
    __syncthreads();
    if (tid == 0) s_psum = (red[0] + red[1]) + (red[2] + red[3]);
    __syncthreads();
    const float psum  = s_psum;
    const float denom = psum + EPSF;

    for (int e = tid; e < O_ * T9; e += 256) {
        const float4* q1 = (const float4*)(part1 + (size_t)(b * 288 + e) * 32);
        const float4* q2 = (const float4*)(part2 + (size_t)(b * 288 + e) * 32);
        float s1 = 0.f, s2 = 0.f;
#pragma unroll
        for (int i = 0; i < 8; ++i) {
            const float4 v1 = q1[i], v2 = q2[i];
            s1 += (v1.x + v1.y) + (v1.z + v1.w);
            s2 += (v2.x + v2.y) + (v2.z + v2.w);
        }
        const float caps = s1 / denom;
        out[(size_t)b * 288 + e] = caps;
        vlds[e] = (s2 - 2.f * caps * s1 + caps * caps * psum) / denom;
    }
    __syncthreads();

    if (tid < O_) {
        float vs = 0.f;
#pragma unroll
        for (int t = 0; t < 9; ++t) vs += vlds[tid * 9 + t];
        float mx = vs;
#pragma unroll
        for (int msk = 1; msk < 32; msk <<= 1) mx = fmaxf(mx, __shfl_xor(mx, msk, 32));
        out[(size_t)B_ * O_ * T9 + b * O_ + tid] = 1.f - vs / (mx + EPSF);
    }
}

extern "C" void kernel_launch(void* const* d_in, const int* in_sizes, int n_in,
                              void* d_out, int out_size, void* d_ws, size_t ws_size,
                              hipStream_t stream)
{
    (void)in_sizes; (void)n_in; (void)out_size; (void)ws_size;
    const float* x = (const float*)d_in[0];   // (16,32,14,14,9)
    const float* p = (const float*)d_in[1];   // (16,32,14,14)
    // d_in[2] = epoch (unused)
    const float* T = (const float*)d_in[3];   // (1,32,32,14,14,9,9)
    float* out = (float*)d_out;

    float* part1 = (float*)d_ws;
    float* part2 = part1 + PART_N;
    float* xT    = part2 + PART_N;
    float* pT    = xT + XT_N;

    caps_pre<<<1024, 256, 0, stream>>>(x, p, xT, pT);
    dim3 gridA(C_, O_);
    caps_main<<<gridA, 256, 0, stream>>>(T, xT, pT, part1, part2);
    caps_final<<<B_, 256, 0, stream>>>(p, part1, part2, out);
}

// Round 5
// 53.386 us; speedup vs baseline: 4.0697x; 4.0697x over previous
//
#include <hip/hip_runtime.h>

#define EPSF 1e-8f

constexpr int B_  = 16;
constexpr int C_  = 32;
constexpr int O_  = 32;
constexpr int HW  = 196;    // 14*14
constexpr int T9  = 9;
constexpr int CH  = 28;     // hw rows per chunk; 196 = 7*28 exact
constexpr int NCH = 7;
constexpr int ROWF = 12;    // padded floats per (hw,t) row
constexpr int CHUNK_F4 = CH * 81 / 4;     // 567 float4 per chunk
constexpr int LDSF = CH * T9 * ROWF;      // 3024 floats = 12096 B
constexpr int PART_N = B_ * O_ * T9 * C_; // 147456
constexpr int XT_N = C_ * B_ * 9 * HW;    // 903168
constexpr int PT_N = C_ * B_ * HW;        // 100352

// ---------------------------------------------------------------------------
// Kernel P: x -> xT[c][b][s][hw] (x0.1 folded), p -> pT[c][b][hw].
// Makes every kernel-A global read lane-contiguous.
// ---------------------------------------------------------------------------
__global__ __launch_bounds__(256) void caps_pre(
    const float* __restrict__ x, const float* __restrict__ p,
    float* __restrict__ xT, float* __restrict__ pT)
{
    const int idx = blockIdx.x * 256 + threadIdx.x;
    const int stride = gridDim.x * 256;
    for (int m = idx; m < XT_N; m += stride) {
        const int hw = m % HW;
        const int r  = m / HW;       // (c*16+b)*9+s
        const int s  = r % 9;
        const int r2 = r / 9;        // c*16+b
        const int b  = r2 % B_;
        const int c  = r2 / B_;
        xT[m] = 0.1f * x[((size_t)(b * C_ + c) * HW + hw) * 9 + s];
    }
    for (int m = idx; m < PT_N; m += stride) {
        const int hw = m % HW;
        const int r2 = m / HW;
        const int b  = r2 % B_;
        const int c  = r2 / B_;
        pT[m] = p[(size_t)(b * C_ + c) * HW + hw];
    }
}

// ---------------------------------------------------------------------------
// Kernel A: block = (o,c). 256 threads: b = tid>>4, r = tid&15.
// Single-buffer 12.1 KB LDS chunk; high occupancy hides stage latency.
// LDS row reads broadcast across the 4 same-r lanes (different b) — free.
// ---------------------------------------------------------------------------
__global__ __launch_bounds__(256) void caps_main(
    const float* __restrict__ T,
    const float* __restrict__ xT, const float* __restrict__ pT,
    float* __restrict__ part1,    // [b][o][t][c]
    float* __restrict__ part2)
{
    const int o   = blockIdx.x;
    const int c   = blockIdx.y;
    const int tid = threadIdx.x;
    const int b   = tid >> 4;
    const int r   = tid & 15;

    __shared__ float tsh[LDSF];

    const float* Tb = T + (size_t)(c * O_ + o) * (HW * 81);
    const float* xb = xT + (size_t)(c * B_ + b) * 9 * HW;
    const float* pb = pT + (size_t)(c * B_ + b) * HW;

    float acc1[9], acc2[9];
#pragma unroll
    for (int t = 0; t < 9; ++t) { acc1[t] = 0.f; acc2[t] = 0.f; }

    for (int k = 0; k < NCH; ++k) {
        if (k) __syncthreads();

        // stage chunk k: coalesced float4 global read, padded scatter to LDS
        const float4* g4 = (const float4*)(Tb + (size_t)k * CH * 81);
#pragma unroll
        for (int q = 0; q < 3; ++q) {
            const int i = tid + q * 256;
            if (i < CHUNK_F4) {
                const float4 v = g4[i];
                const int e = i * 4;
#pragma unroll
                for (int k2 = 0; k2 < 4; ++k2) {
                    const int e2 = e + k2;
                    tsh[e2 + 3 * (e2 / 9)] = ((const float*)&v)[k2];
                }
            }
        }
        __syncthreads();

#pragma unroll
        for (int rep = 0; rep < 2; ++rep) {
            const int row = rep * 16 + r;
            if (row < CH) {
                const int hw = k * CH + row;
                float xr[9];
#pragma unroll
                for (int s = 0; s < 9; ++s) xr[s] = xb[(size_t)s * HW + hw];
                const float pf = pb[hw];
                const float* rowb = tsh + row * (T9 * ROWF);
#pragma unroll
                for (int t = 0; t < 9; ++t) {
                    const float4 ta = *(const float4*)(rowb + t * ROWF);
                    const float4 tb = *(const float4*)(rowb + t * ROWF + 4);
                    const float t8  = rowb[t * ROWF + 8];
                    float pr = ta.x * xr[0];
                    pr = fmaf(ta.y, xr[1], pr);
                    pr = fmaf(ta.z, xr[2], pr);
                    pr = fmaf(ta.w, xr[3], pr);
                    pr = fmaf(tb.x, xr[4], pr);
                    pr = fmaf(tb.y, xr[5], pr);
                    pr = fmaf(tb.z, xr[6], pr);
                    pr = fmaf(tb.w, xr[7], pr);
                    pr = fmaf(t8,   xr[8], pr);
                    const float q1 = pf * pr;
                    acc1[t] += q1;
                    acc2[t] = fmaf(q1, pr, acc2[t]);
                }
            }
        }
    }

    // reduce over the 16 r-lanes (low 4 bits of lane id)
#pragma unroll
    for (int t = 0; t < 9; ++t) {
        float v1 = acc1[t], v2 = acc2[t];
#pragma unroll
        for (int m = 1; m < 16; m <<= 1) {
            v1 += __shfl_xor(v1, m, 64);
            v2 += __shfl_xor(v2, m, 64);
        }
        if (r == 0) {
            const size_t base = ((size_t)(b * O_ + o) * 9 + t) * C_ + c;
            part1[base] = v1;
            part2[base] = v2;
        }
    }
}

// ---------------------------------------------------------------------------
// Kernel B: per-b finalize. psum, c-reduction (float4), caps/var/vs/p_upd.
// ---------------------------------------------------------------------------
__global__ __launch_bounds__(256) void caps_final(
    const float* __restrict__ p,
    const float* __restrict__ part1, const float* __restrict__ part2,
    float* __restrict__ out)          // caps [B][O][9] then p_updated [B][O]
{
    const int b   = blockIdx.x;
    const int tid = threadIdx.x;

    __shared__ float vlds[O_ * T9];
    __shared__ float red[4];
    __shared__ float s_psum;

    const float* pb = p + (size_t)b * (C_ * HW);
    float a = 0.f;
    for (int i = tid; i < C_ * HW; i += 256) a += pb[i];
#pragma unroll
    for (int m = 1; m < 64; m <<= 1) a += __shfl_xor(a, m, 64);
    if ((tid & 63) == 0) red[tid >> 6] = a;
    __syncthreads();
    if (tid == 0) s_psum = (red[0] + red[1]) + (red[2] + red[3]);
    __syncthreads();
    const float psum  = s_psum;
    const float denom = psum + EPSF;

    for (int e = tid; e < O_ * T9; e += 256) {
        const float4* q1 = (const float4*)(part1 + (size_t)(b * 288 + e) * 32);
        const float4* q2 = (const float4*)(part2 + (size_t)(b * 288 + e) * 32);
        float s1 = 0.f, s2 = 0.f;
#pragma unroll
        for (int i = 0; i < 8; ++i) {
            const float4 v1 = q1[i], v2 = q2[i];
            s1 += (v1.x + v1.y) + (v1.z + v1.w);
            s2 += (v2.x + v2.y) + (v2.z + v2.w);
        }
        const float caps = s1 / denom;
        out[(size_t)b * 288 + e] = caps;
        vlds[e] = (s2 - 2.f * caps * s1 + caps * caps * psum) / denom;
    }
    __syncthreads();

    if (tid < O_) {
        float vs = 0.f;
#pragma unroll
        for (int t = 0; t < 9; ++t) vs += vlds[tid * 9 + t];
        float mx = vs;
#pragma unroll
        for (int msk = 1; msk < 32; msk <<= 1) mx = fmaxf(mx, __shfl_xor(mx, msk, 32));
        out[(size_t)B_ * O_ * T9 + b * O_ + tid] = 1.f - vs / (mx + EPSF);
    }
}

extern "C" void kernel_launch(void* const* d_in, const int* in_sizes, int n_in,
                              void* d_out, int out_size, void* d_ws, size_t ws_size,
                              hipStream_t stream)
{
    (void)in_sizes; (void)n_in; (void)out_size; (void)ws_size;
    const float* x = (const float*)d_in[0];   // (16,32,14,14,9)
    const float* p = (const float*)d_in[1];   // (16,32,14,14)
    // d_in[2] = epoch (unused)
    const float* T = (const float*)d_in[3];   // (1,32,32,14,14,9,9)
    float* out = (float*)d_out;

    float* part1 = (float*)d_ws;
    float* part2 = part1 + PART_N;
    float* xT    = part2 + PART_N;
    float* pT    = xT + XT_N;

    caps_pre<<<1024, 256, 0, stream>>>(x, p, xT, pT);
    dim3 gridA(O_, C_);   // x = o (fast) so same-c blocks are adjacent -> L2 reuse of xT
    caps_main<<<gridA, 256, 0, stream>>>(T, xT, pT, part1, part2);
    caps_final<<<B_, 256, 0, stream>>>(p, part1, part2, out);
}